// Round 1
// 4899.008 us; speedup vs baseline: 1.3622x; 1.3622x over previous
//
#include <hip/hip_runtime.h>
#include <cmath>

#define S_LEN 128
#define BATCH 32
#define HID   512
#define VOCAB 10000
#define MROWS (S_LEN * BATCH)   // 4096
#define HH    (HID * HID)

#define NBLK  64
#define NTHR  512

// ---------------------------------------------------------------------------
// Tiled fp32 GEMM: C[M,N] = A[M,K] * B + bias[N]   (unchanged from prior round)
// ---------------------------------------------------------------------------
template<bool GATHER_A, bool B_KN>
__global__ __launch_bounds__(256) void gemm_kernel(
    const float* __restrict__ A, const int* __restrict__ tok,
    const float* __restrict__ Bmat, const float* __restrict__ bias,
    float* __restrict__ C, int M, int N, int K)
{
    __shared__ float As[32][68];
    __shared__ float Bs[32][68];
    __shared__ int   toks[64];

    const int tid = threadIdx.x;
    const int m0  = blockIdx.y * 64;
    const int n0  = blockIdx.x * 64;

    if (GATHER_A && tid < 64) toks[tid] = tok[m0 + tid];
    __syncthreads();

    const int tx = tid & 15;
    const int ty = tid >> 4;
    const int lr = tid >> 3;
    const int lc = (tid & 7) * 4;

    float acc[4][4] = {};

    for (int k0 = 0; k0 < K; k0 += 32) {
        #pragma unroll
        for (int rep = 0; rep < 2; rep++) {
            int r = lr + rep * 32;
            const float* arow;
            if (GATHER_A) arow = A + (size_t)toks[r] * K;
            else          arow = A + (size_t)(m0 + r) * K;
            float4 v = *(const float4*)(arow + k0 + lc);
            As[lc + 0][r] = v.x; As[lc + 1][r] = v.y;
            As[lc + 2][r] = v.z; As[lc + 3][r] = v.w;
        }
        if (B_KN) {
            int g    = n0 >> 9;
            int col0 = n0 & 511;
            const float* bbase = Bmat + (size_t)g * K * 512 + col0;
            int bc = (tid & 15) * 4;
            int bk = tid >> 4;
            #pragma unroll
            for (int rep = 0; rep < 2; rep++) {
                int kk = bk + rep * 16;
                float4 v = *(const float4*)(bbase + (size_t)(k0 + kk) * 512 + bc);
                *(float4*)&Bs[kk][bc] = v;
            }
        } else {
            #pragma unroll
            for (int rep = 0; rep < 2; rep++) {
                int r = lr + rep * 32;
                int n = n0 + r;
                float4 v = make_float4(0.f, 0.f, 0.f, 0.f);
                if (n < N) v = *(const float4*)(Bmat + (size_t)n * K + k0 + lc);
                Bs[lc + 0][r] = v.x; Bs[lc + 1][r] = v.y;
                Bs[lc + 2][r] = v.z; Bs[lc + 3][r] = v.w;
            }
        }
        __syncthreads();
        #pragma unroll
        for (int k = 0; k < 32; k++) {
            float4 a4 = *(const float4*)&As[k][ty * 4];
            float4 b4 = *(const float4*)&Bs[k][tx * 4];
            float av[4] = {a4.x, a4.y, a4.z, a4.w};
            float bv[4] = {b4.x, b4.y, b4.z, b4.w};
            #pragma unroll
            for (int i = 0; i < 4; i++)
                #pragma unroll
                for (int j = 0; j < 4; j++)
                    acc[i][j] = fmaf(av[i], bv[j], acc[i][j]);
        }
        __syncthreads();
    }
    #pragma unroll
    for (int i = 0; i < 4; i++) {
        int m = m0 + ty * 4 + i;
        #pragma unroll
        for (int j = 0; j < 4; j++) {
            int n = n0 + tx * 4 + j;
            if (n < N) C[(size_t)m * N + n] = acc[i][j] + bias[n];
        }
    }
}

// ---------------------------------------------------------------------------
// Device-wide spin barrier (monotonic counter, agent scope).
// 64 blocks x 1 block/CU (LDS-bound) => guaranteed co-resident.
// ---------------------------------------------------------------------------
__device__ __forceinline__ void grid_bar(unsigned* bar, unsigned target)
{
    __syncthreads();                       // drains each thread's stores to L2
    if (threadIdx.x == 0) {
        __hip_atomic_fetch_add(bar, 1u, __ATOMIC_RELEASE, __HIP_MEMORY_SCOPE_AGENT);
        while (__hip_atomic_load(bar, __ATOMIC_ACQUIRE, __HIP_MEMORY_SCOPE_AGENT) < target)
            __builtin_amdgcn_s_sleep(1);
    }
    __syncthreads();
}

// ---------------------------------------------------------------------------
// Cooperative column-split GRU layer scan.
// 64 blocks x 512 threads. Block i owns:
//   - 16 r/z columns: global rz col cc0=i*16 (gate g=i/32, in-gate base cg0)
//   - 8  h_hat columns: ch0=i*8
// Weight slices live in LDS for the whole launch (loaded once).
// Per step: P1 (r,z dots) -> barrier -> P2 (h_hat dots + blend) -> barrier.
// LDS tiles stored [row][512] with float4-granular XOR swizzle (k4 ^= row&7)
// so strided row reads are bank-conflict-free.
// r-blocks write v = r*h directly to rzbuf[:, 0:512]; z in rzbuf[:, 512:1024].
// ---------------------------------------------------------------------------
__global__ __launch_bounds__(NTHR) void scan_coop_kernel(
    const float* __restrict__ ax, const float* __restrict__ Ul,
    const float* __restrict__ h0g, float* __restrict__ hseq,
    float* __restrict__ hfin, float* __restrict__ hglob,
    float* __restrict__ rzbuf, unsigned* __restrict__ bar)
{
    __shared__ float Wrz[16 * 512];   // 32 KB  [c][k] swizzled
    __shared__ float Whh[8 * 512];    // 16 KB  [c][k] swizzled
    __shared__ float xbuf[32 * 512];  // 64 KB  h(t-1), then v=r*h  [b][k] swizzled
    __shared__ float part[16 * 512];  // 32 KB  k-split partials

    const int tid = threadIdx.x;
    const int bid = blockIdx.x;
    const int g   = bid >> 5;             // rz gate: 0=r, 1=z
    const int cg0 = (bid & 31) << 4;      // col base within gate
    const int cc0 = bid << 4;             // global rz col base (0..1008)
    const int ch0 = bid << 3;             // h_hat col base (0..504)

    // ---- one-time weight preload into LDS (global reads coalesced over c) ----
    for (int idx = tid; idx < 16 * 512; idx += NTHR) {
        int c = idx & 15, k = idx >> 4;
        Wrz[c * 512 + ((((k >> 2) ^ (c & 7)) << 2) | (k & 3))] =
            Ul[(size_t)g * HH + (size_t)k * HID + cg0 + c];
    }
    for (int idx = tid; idx < 8 * 512; idx += NTHR) {
        int c = idx & 7, k = idx >> 3;
        Whh[c * 512 + ((((k >> 2) ^ (c & 7)) << 2) | (k & 3))] =
            Ul[(size_t)2 * HH + (size_t)k * HID + ch0 + c];
    }

    const int ks = tid >> 5;          // k-slice 0..15 (K=32 each)
    const int ct = (tid >> 3) & 3;    // c-tile
    const int bt = tid & 7;           // b-tile
    unsigned barcnt = 0;

    for (int t = 0; t < S_LEN; t++) {
        // ---- stage xbuf = h(t-1), swizzled ----
        const float* hsrc = t ? hglob : h0g;
        for (int idx = tid; idx < 4096; idx += NTHR) {
            int b = idx >> 7, k4 = idx & 127;
            float4 hv4 = *(const float4*)(hsrc + b * HID + (k4 << 2));
            *(float4*)&xbuf[b * 512 + ((k4 ^ (b & 7)) << 2)] = hv4;
        }
        __syncthreads();

        // ---- P1 dot: own 16 r/z columns, 4c x 4b microtile, 16-way k-split ----
        {
            float acc[4][4] = {};
            #pragma unroll
            for (int it = 0; it < 8; it++) {
                int k4 = (ks << 3) + it;
                float4 wv[4], hv[4];
                #pragma unroll
                for (int i = 0; i < 4; i++) {
                    int c = ct + (i << 2);
                    wv[i] = *(const float4*)&Wrz[c * 512 + ((k4 ^ (c & 7)) << 2)];
                }
                #pragma unroll
                for (int j = 0; j < 4; j++) {
                    int b = bt + (j << 3);
                    hv[j] = *(const float4*)&xbuf[b * 512 + ((k4 ^ (b & 7)) << 2)];
                }
                #pragma unroll
                for (int i = 0; i < 4; i++)
                    #pragma unroll
                    for (int j = 0; j < 4; j++)
                        acc[i][j] += wv[i].x * hv[j].x + wv[i].y * hv[j].y
                                   + wv[i].z * hv[j].z + wv[i].w * hv[j].w;
            }
            #pragma unroll
            for (int i = 0; i < 4; i++)
                #pragma unroll
                for (int j = 0; j < 4; j++)
                    part[(ks << 9) + (ct + (i << 2)) * 32 + bt + (j << 3)] = acc[i][j];
        }
        __syncthreads();

        // ---- P1 reduce + sigmoid; r-blocks write v=r*h, z-blocks write z ----
        {
            int c = tid >> 5, b = tid & 31;           // 512 outputs, 1/thread
            float s = 0.f;
            #pragma unroll
            for (int q = 0; q < 16; q++) s += part[(q << 9) + tid];
            int cc = cc0 + c;
            float pre = ax[(size_t)((t << 5) + b) * 1536 + cc] + s;
            float sig = 1.f / (1.f + __expf(-pre));
            float outv;
            if (g == 0)
                outv = sig * xbuf[b * 512 + (((cc >> 2) ^ (b & 7)) << 2) + (cc & 3)];
            else
                outv = sig;
            rzbuf[(b << 10) + cc] = outv;
        }
        barcnt++; grid_bar(bar, barcnt * NBLK);

        // ---- P2: save h,z for own cols, then xbuf = v ----
        float h_own = 0.f, z_own = 0.f;
        if (tid < 256) {
            int c = tid >> 5, b = tid & 31;
            int hc = ch0 + c;
            h_own = xbuf[b * 512 + (((hc >> 2) ^ (b & 7)) << 2) + (hc & 3)];
            z_own = rzbuf[(b << 10) + 512 + hc];
        }
        __syncthreads();
        for (int idx = tid; idx < 4096; idx += NTHR) {
            int b = idx >> 7, k4 = idx & 127;
            float4 vv4 = *(const float4*)(rzbuf + (b << 10) + (k4 << 2));
            *(float4*)&xbuf[b * 512 + ((k4 ^ (b & 7)) << 2)] = vv4;
        }
        __syncthreads();

        // ---- P2 dot: own 8 h_hat columns, 2c x 4b microtile, 16-way k-split ----
        {
            float acc[2][4] = {};
            #pragma unroll
            for (int it = 0; it < 8; it++) {
                int k4 = (ks << 3) + it;
                float4 wv[2], vv[4];
                #pragma unroll
                for (int i = 0; i < 2; i++) {
                    int c = ct + (i << 2);
                    wv[i] = *(const float4*)&Whh[c * 512 + ((k4 ^ (c & 7)) << 2)];
                }
                #pragma unroll
                for (int j = 0; j < 4; j++) {
                    int b = bt + (j << 3);
                    vv[j] = *(const float4*)&xbuf[b * 512 + ((k4 ^ (b & 7)) << 2)];
                }
                #pragma unroll
                for (int i = 0; i < 2; i++)
                    #pragma unroll
                    for (int j = 0; j < 4; j++)
                        acc[i][j] += wv[i].x * vv[j].x + wv[i].y * vv[j].y
                                   + wv[i].z * vv[j].z + wv[i].w * vv[j].w;
            }
            #pragma unroll
            for (int i = 0; i < 2; i++)
                #pragma unroll
                for (int j = 0; j < 4; j++)
                    part[(ks << 8) + (ct + (i << 2)) * 32 + bt + (j << 3)] = acc[i][j];
        }
        __syncthreads();

        // ---- P2 reduce + tanh + blend + writeback ----
        if (tid < 256) {
            int c = tid >> 5, b = tid & 31;
            float s = 0.f;
            #pragma unroll
            for (int q = 0; q < 16; q++) s += part[(q << 8) + tid];
            float pre = ax[(size_t)((t << 5) + b) * 1536 + 1024 + ch0 + c] + s;
            float e2 = __expf(2.f * pre);
            float hh_t = 1.f - 2.f / (e2 + 1.f);     // tanh
            float hn = (1.f - z_own) * h_own + z_own * hh_t;
            hglob[b * HID + ch0 + c] = hn;
            hseq[(size_t)((t << 5) + b) * HID + ch0 + c] = hn;
            if (t == S_LEN - 1) hfin[b * HID + ch0 + c] = hn;
        }
        barcnt++; grid_bar(bar, barcnt * NBLK);
    }
}

// ---------------------------------------------------------------------------
extern "C" void kernel_launch(void* const* d_in, const int* in_sizes, int n_in,
                              void* d_out, int out_size, void* d_ws, size_t ws_size,
                              hipStream_t stream)
{
    const int*   tokens = (const int*)  d_in[0];   // [S,B] (int32 after jax x64-off)
    const float* h0     = (const float*)d_in[1];   // [L,B,H]
    const float* emb    = (const float*)d_in[2];   // [V,H]
    const float* Wx     = (const float*)d_in[3];   // [L,3,H,H]
    const float* bx     = (const float*)d_in[4];   // [L,3,H]
    const float* U      = (const float*)d_in[5];   // [L,3,H,H]
    const float* Wy     = (const float*)d_in[6];   // [V,H]
    const float* by     = (const float*)d_in[7];   // [V]
    float*       out    = (float*)d_out;

    // workspace: axbuf [4096*1536]; hseq [4096*512]
    float* ws    = (float*)d_ws;
    float* axbuf = ws;
    float* hseq  = axbuf + (size_t)MROWS * 1536;

    const size_t logits_sz = (size_t)MROWS * VOCAB;
    float* hfin0 = out + logits_sz;
    float* hfin1 = out + logits_sz + BATCH * HID;

    // scratch carved from the logits region (overwritten by final GEMM):
    //   hglob [32*512], rzbuf [32*1024], 2 barrier counters
    float*    hglob = out;
    float*    rzbuf = out + BATCH * HID;                       // +16384
    unsigned* bars  = (unsigned*)(out + BATCH * HID + BATCH * 1024); // +49152
    hipMemsetAsync(bars, 0, 2 * sizeof(unsigned), stream);

    // ax0 = emb[tokens] @ Wx[0] + bx[0]
    gemm_kernel<true, true><<<dim3(1536 / 64, MROWS / 64), 256, 0, stream>>>(
        emb, tokens, Wx, bx, axbuf, MROWS, 1536, HID);

    // layer-0 scan (column-split cooperative)
    scan_coop_kernel<<<NBLK, NTHR, 0, stream>>>(
        axbuf, U, h0, hseq, hfin0, hglob, rzbuf, bars + 0);

    // ax1 = hseq @ Wx[1] + bx[1]
    gemm_kernel<false, true><<<dim3(1536 / 64, MROWS / 64), 256, 0, stream>>>(
        hseq, nullptr, Wx + 3 * HH, bx + 1536, axbuf, MROWS, 1536, HID);

    // layer-1 scan
    scan_coop_kernel<<<NBLK, NTHR, 0, stream>>>(
        axbuf, U + 3 * HH, h0 + BATCH * HID, hseq, hfin1, hglob, rzbuf, bars + 1);

    // logits = tops @ Wy^T + by
    gemm_kernel<false, false><<<dim3((VOCAB + 63) / 64, MROWS / 64), 256, 0, stream>>>(
        hseq, nullptr, Wy, by, out, MROWS, VOCAB, HID);
}

// Round 2
// 4405.084 us; speedup vs baseline: 1.5150x; 1.1121x over previous
//
#include <hip/hip_runtime.h>
#include <cmath>

#define S_LEN 128
#define BATCH 32
#define HID   512
#define VOCAB 10000
#define MROWS (S_LEN * BATCH)   // 4096
#define HH    (HID * HID)

#define NBLK  64
#define NTHR  512

typedef float f32x4_t __attribute__((ext_vector_type(4)));

// ---------------------------------------------------------------------------
// Tiled fp32 GEMM: C[M,N] = A[M,K] * B + bias[N]   (unchanged)
// ---------------------------------------------------------------------------
template<bool GATHER_A, bool B_KN>
__global__ __launch_bounds__(256) void gemm_kernel(
    const float* __restrict__ A, const int* __restrict__ tok,
    const float* __restrict__ Bmat, const float* __restrict__ bias,
    float* __restrict__ C, int M, int N, int K)
{
    __shared__ float As[32][68];
    __shared__ float Bs[32][68];
    __shared__ int   toks[64];

    const int tid = threadIdx.x;
    const int m0  = blockIdx.y * 64;
    const int n0  = blockIdx.x * 64;

    if (GATHER_A && tid < 64) toks[tid] = tok[m0 + tid];
    __syncthreads();

    const int tx = tid & 15;
    const int ty = tid >> 4;
    const int lr = tid >> 3;
    const int lc = (tid & 7) * 4;

    float acc[4][4] = {};

    for (int k0 = 0; k0 < K; k0 += 32) {
        #pragma unroll
        for (int rep = 0; rep < 2; rep++) {
            int r = lr + rep * 32;
            const float* arow;
            if (GATHER_A) arow = A + (size_t)toks[r] * K;
            else          arow = A + (size_t)(m0 + r) * K;
            float4 v = *(const float4*)(arow + k0 + lc);
            As[lc + 0][r] = v.x; As[lc + 1][r] = v.y;
            As[lc + 2][r] = v.z; As[lc + 3][r] = v.w;
        }
        if (B_KN) {
            int g    = n0 >> 9;
            int col0 = n0 & 511;
            const float* bbase = Bmat + (size_t)g * K * 512 + col0;
            int bc = (tid & 15) * 4;
            int bk = tid >> 4;
            #pragma unroll
            for (int rep = 0; rep < 2; rep++) {
                int kk = bk + rep * 16;
                float4 v = *(const float4*)(bbase + (size_t)(k0 + kk) * 512 + bc);
                *(float4*)&Bs[kk][bc] = v;
            }
        } else {
            #pragma unroll
            for (int rep = 0; rep < 2; rep++) {
                int r = lr + rep * 32;
                int n = n0 + r;
                float4 v = make_float4(0.f, 0.f, 0.f, 0.f);
                if (n < N) v = *(const float4*)(Bmat + (size_t)n * K + k0 + lc);
                Bs[lc + 0][r] = v.x; Bs[lc + 1][r] = v.y;
                Bs[lc + 2][r] = v.z; Bs[lc + 3][r] = v.w;
            }
        }
        __syncthreads();
        #pragma unroll
        for (int k = 0; k < 32; k++) {
            float4 a4 = *(const float4*)&As[k][ty * 4];
            float4 b4 = *(const float4*)&Bs[k][tx * 4];
            float av[4] = {a4.x, a4.y, a4.z, a4.w};
            float bv[4] = {b4.x, b4.y, b4.z, b4.w};
            #pragma unroll
            for (int i = 0; i < 4; i++)
                #pragma unroll
                for (int j = 0; j < 4; j++)
                    acc[i][j] = fmaf(av[i], bv[j], acc[i][j]);
        }
        __syncthreads();
    }
    #pragma unroll
    for (int i = 0; i < 4; i++) {
        int m = m0 + ty * 4 + i;
        #pragma unroll
        for (int j = 0; j < 4; j++) {
            int n = n0 + tx * 4 + j;
            if (n < N) C[(size_t)m * N + n] = acc[i][j] + bias[n];
        }
    }
}

// ---------------------------------------------------------------------------
// Agent-coherent (LLC-direct) access helpers. sc1 loads/stores bypass the
// non-coherent per-XCD L2 and hit the shared Infinity Cache — cross-block
// data exchange without any cache flush/invalidate.
// Caller MUST execute an explicit "s_waitcnt vmcnt(0)" asm before consuming
// ldg_coh_x4 results (ds_write consumers are ordered by the memory clobber).
// ---------------------------------------------------------------------------
__device__ __forceinline__ f32x4_t ldg_coh_x4(const float* p) {
    f32x4_t r;
    asm volatile("global_load_dwordx4 %0, %1, off sc1"
                 : "=v"(r) : "v"(p) : "memory");
    return r;
}
__device__ __forceinline__ void stg_coh(float* p, float v) {
    asm volatile("global_store_dword %0, %1, off sc1"
                 :: "v"(p), "v"(v) : "memory");
}

// ---------------------------------------------------------------------------
// Contention-free device barrier: per-block monotonic flags (no shared-line
// RMW), wave0 polls all 64 flags in parallel with relaxed agent loads.
// The RELEASE flag store drains this wave's vmem; the explicit waitcnt before
// __syncthreads drains every other wave's asm sc1 stores.
// ---------------------------------------------------------------------------
__device__ __forceinline__ void flag_bar(unsigned* flags, int bid, unsigned target)
{
    asm volatile("s_waitcnt vmcnt(0)" ::: "memory");
    __syncthreads();
    if (threadIdx.x == 0)
        __hip_atomic_store(&flags[bid], target, __ATOMIC_RELEASE, __HIP_MEMORY_SCOPE_AGENT);
    if (threadIdx.x < NBLK) {
        while (__hip_atomic_load(&flags[threadIdx.x], __ATOMIC_RELAXED,
                                 __HIP_MEMORY_SCOPE_AGENT) < target)
            __builtin_amdgcn_s_sleep(1);
    }
    __syncthreads();
}

// ---------------------------------------------------------------------------
// Cooperative column-split GRU layer scan (64 blocks x 512 threads).
// Block i owns 16 r/z columns (cc0=i*16) and 8 h_hat columns (ch0=i*8).
// Weights LDS-resident for the whole launch. Cross-block exchange (v=r*h, z,
// h via hseq rows) goes through the LLC with sc1 ops; 2 flag barriers/step.
// part[] stores XOR-swizzled (c<<5 | b^c): conflict-free store AND reduce.
// ---------------------------------------------------------------------------
__global__ __launch_bounds__(NTHR) void scan_coop_kernel(
    const float* __restrict__ ax, const float* __restrict__ Ul,
    const float* __restrict__ h0g, float* __restrict__ hseq,
    float* __restrict__ hfin, float* __restrict__ rzbuf,
    unsigned* __restrict__ flags)
{
    __shared__ float Wrz[16 * 512];   // 32 KB  [c][k] swizzled
    __shared__ float Whh[8 * 512];    // 16 KB  [c][k] swizzled
    __shared__ float xbuf[32 * 512];  // 64 KB  h(t-1), then v=r*h  [b][k] swizzled
    __shared__ float part[16 * 512];  // 32 KB  k-split partials (XOR-swizzled)

    const int tid = threadIdx.x;
    const int bid = blockIdx.x;
    const int g   = bid >> 5;             // rz gate: 0=r, 1=z
    const int cg0 = (bid & 31) << 4;      // col base within gate
    const int cc0 = bid << 4;             // global rz col base (0..1008)
    const int ch0 = bid << 3;             // h_hat col base (0..504)

    // ---- one-time weight preload into LDS ----
    for (int idx = tid; idx < 16 * 512; idx += NTHR) {
        int c = idx & 15, k = idx >> 4;
        Wrz[c * 512 + ((((k >> 2) ^ (c & 7)) << 2) | (k & 3))] =
            Ul[(size_t)g * HH + (size_t)k * HID + cg0 + c];
    }
    for (int idx = tid; idx < 8 * 512; idx += NTHR) {
        int c = idx & 7, k = idx >> 3;
        Whh[c * 512 + ((((k >> 2) ^ (c & 7)) << 2) | (k & 3))] =
            Ul[(size_t)2 * HH + (size_t)k * HID + ch0 + c];
    }

    const int ks = tid >> 5;          // k-slice 0..15 (K=32 each)
    const int ct = (tid >> 3) & 3;    // c-tile
    const int bt = tid & 7;           // b-tile
    const int rb = tid & 31;          // reduce-phase batch
    const int rc = tid >> 5;          // reduce-phase col

    for (int t = 0; t < S_LEN; t++) {
        // ---- prefetch ax terms for this step (normal loads, compiler-tracked)
        const size_t axrow = (size_t)((t << 5) + rb) * 1536;
        float ax1 = ax[axrow + cc0 + rc];
        float ax2 = (tid < 256) ? ax[axrow + 1024 + ch0 + rc] : 0.f;

        // ---- stage xbuf = h(t-1) from hseq rows (or h0), coherent loads ----
        {
            const float* hsrc = t ? (hseq + (size_t)(t - 1) * BATCH * HID) : h0g;
            f32x4_t ld[8];
            #pragma unroll
            for (int i = 0; i < 8; i++) {
                int idx = tid + i * NTHR;
                int b = idx >> 7, k4 = idx & 127;
                ld[i] = ldg_coh_x4(hsrc + b * HID + (k4 << 2));
            }
            asm volatile("s_waitcnt vmcnt(0)" ::: "memory");
            #pragma unroll
            for (int i = 0; i < 8; i++) {
                int idx = tid + i * NTHR;
                int b = idx >> 7, k4 = idx & 127;
                *(f32x4_t*)&xbuf[b * 512 + ((k4 ^ (b & 7)) << 2)] = ld[i];
            }
        }
        __syncthreads();

        // ---- P1 dot: 16 r/z columns, 4c x 4b microtile, 16-way k-split ----
        {
            float acc[4][4] = {};
            #pragma unroll
            for (int it = 0; it < 8; it++) {
                int k4 = (ks << 3) + it;
                f32x4_t wv[4], hv[4];
                #pragma unroll
                for (int i = 0; i < 4; i++) {
                    int c = ct + (i << 2);
                    wv[i] = *(const f32x4_t*)&Wrz[c * 512 + ((k4 ^ (c & 7)) << 2)];
                }
                #pragma unroll
                for (int j = 0; j < 4; j++) {
                    int b = bt + (j << 3);
                    hv[j] = *(const f32x4_t*)&xbuf[b * 512 + ((k4 ^ (b & 7)) << 2)];
                }
                #pragma unroll
                for (int i = 0; i < 4; i++)
                    #pragma unroll
                    for (int j = 0; j < 4; j++)
                        acc[i][j] += wv[i].x * hv[j].x + wv[i].y * hv[j].y
                                   + wv[i].z * hv[j].z + wv[i].w * hv[j].w;
            }
            #pragma unroll
            for (int i = 0; i < 4; i++)
                #pragma unroll
                for (int j = 0; j < 4; j++) {
                    int c = ct + (i << 2), b = bt + (j << 3);
                    part[(ks << 9) + (c << 5) + (b ^ c)] = acc[i][j];
                }
        }
        __syncthreads();

        // ---- P1 reduce + sigmoid; publish v=r*h (g=0) or z (g=1) via LLC ----
        {
            float s = 0.f;
            #pragma unroll
            for (int q = 0; q < 16; q++) s += part[(q << 9) + (rc << 5) + (rb ^ rc)];
            int cc = cc0 + rc;
            float pre = ax1 + s;
            float sig = 1.f / (1.f + __expf(-pre));
            float outv;
            if (g == 0)
                outv = sig * xbuf[rb * 512 + (((cc >> 2) ^ (rb & 7)) << 2) + (cc & 3)];
            else
                outv = sig;
            stg_coh(rzbuf + (rb << 10) + cc, outv);
        }
        flag_bar(flags, bid, 2 * t + 1);

        // ---- grab own z slice + own h before xbuf is overwritten ----
        float z_own = 0.f, h_own = 0.f;
        if (tid < 256) {
            z_own = __hip_atomic_load(rzbuf + (rb << 10) + 512 + ch0 + rc,
                                      __ATOMIC_RELAXED, __HIP_MEMORY_SCOPE_AGENT);
            int hc = ch0 + rc;
            h_own = xbuf[rb * 512 + (((hc >> 2) ^ (rb & 7)) << 2) + (hc & 3)];
        }
        __syncthreads();

        // ---- stage xbuf = v (full 32x512), coherent loads ----
        {
            f32x4_t ld[8];
            #pragma unroll
            for (int i = 0; i < 8; i++) {
                int idx = tid + i * NTHR;
                int b = idx >> 7, k4 = idx & 127;
                ld[i] = ldg_coh_x4(rzbuf + (b << 10) + (k4 << 2));
            }
            asm volatile("s_waitcnt vmcnt(0)" ::: "memory");
            #pragma unroll
            for (int i = 0; i < 8; i++) {
                int idx = tid + i * NTHR;
                int b = idx >> 7, k4 = idx & 127;
                *(f32x4_t*)&xbuf[b * 512 + ((k4 ^ (b & 7)) << 2)] = ld[i];
            }
        }
        __syncthreads();

        // ---- P2 dot: 8 h_hat columns, 2c x 4b microtile, 16-way k-split ----
        {
            float acc[2][4] = {};
            #pragma unroll
            for (int it = 0; it < 8; it++) {
                int k4 = (ks << 3) + it;
                f32x4_t wv[2], vv[4];
                #pragma unroll
                for (int i = 0; i < 2; i++) {
                    int c = ct + (i << 2);
                    wv[i] = *(const f32x4_t*)&Whh[c * 512 + ((k4 ^ (c & 7)) << 2)];
                }
                #pragma unroll
                for (int j = 0; j < 4; j++) {
                    int b = bt + (j << 3);
                    vv[j] = *(const f32x4_t*)&xbuf[b * 512 + ((k4 ^ (b & 7)) << 2)];
                }
                #pragma unroll
                for (int i = 0; i < 2; i++)
                    #pragma unroll
                    for (int j = 0; j < 4; j++)
                        acc[i][j] += wv[i].x * vv[j].x + wv[i].y * vv[j].y
                                   + wv[i].z * vv[j].z + wv[i].w * vv[j].w;
            }
            #pragma unroll
            for (int i = 0; i < 2; i++)
                #pragma unroll
                for (int j = 0; j < 4; j++) {
                    int c = ct + (i << 2), b = bt + (j << 3);
                    part[(ks << 8) + (c << 5) + (b ^ c)] = acc[i][j];
                }
        }
        __syncthreads();

        // ---- P2 reduce + tanh + blend; publish h via hseq (coherent) ----
        if (tid < 256) {
            float s = 0.f;
            #pragma unroll
            for (int q = 0; q < 16; q++) s += part[(q << 8) + (rc << 5) + (rb ^ rc)];
            float pre = ax2 + s;
            float e2 = __expf(2.f * pre);
            float hh_t = 1.f - 2.f / (e2 + 1.f);     // tanh
            float hn = (1.f - z_own) * h_own + z_own * hh_t;
            stg_coh(hseq + (size_t)((t << 5) + rb) * HID + ch0 + rc, hn);
            if (t == S_LEN - 1) hfin[rb * HID + ch0 + rc] = hn;
        }
        flag_bar(flags, bid, 2 * t + 2);
    }
}

// ---------------------------------------------------------------------------
extern "C" void kernel_launch(void* const* d_in, const int* in_sizes, int n_in,
                              void* d_out, int out_size, void* d_ws, size_t ws_size,
                              hipStream_t stream)
{
    const int*   tokens = (const int*)  d_in[0];   // [S,B]
    const float* h0     = (const float*)d_in[1];   // [L,B,H]
    const float* emb    = (const float*)d_in[2];   // [V,H]
    const float* Wx     = (const float*)d_in[3];   // [L,3,H,H]
    const float* bx     = (const float*)d_in[4];   // [L,3,H]
    const float* U      = (const float*)d_in[5];   // [L,3,H,H]
    const float* Wy     = (const float*)d_in[6];   // [V,H]
    const float* by     = (const float*)d_in[7];   // [V]
    float*       out    = (float*)d_out;

    // workspace: axbuf [4096*1536]; hseq [4096*512]
    float* ws    = (float*)d_ws;
    float* axbuf = ws;
    float* hseq  = axbuf + (size_t)MROWS * 1536;

    const size_t logits_sz = (size_t)MROWS * VOCAB;
    float* hfin0 = out + logits_sz;
    float* hfin1 = out + logits_sz + BATCH * HID;

    // scratch carved from the logits region (overwritten by the final GEMM):
    //   rzbuf [32 x 1024], 2 x 64 barrier flags
    float*    rzbuf = out;
    unsigned* flags = (unsigned*)(out + BATCH * 1024);
    hipMemsetAsync(flags, 0, 2 * NBLK * sizeof(unsigned), stream);

    // ax0 = emb[tokens] @ Wx[0] + bx[0]
    gemm_kernel<true, true><<<dim3(1536 / 64, MROWS / 64), 256, 0, stream>>>(
        emb, tokens, Wx, bx, axbuf, MROWS, 1536, HID);

    // layer-0 scan
    scan_coop_kernel<<<NBLK, NTHR, 0, stream>>>(
        axbuf, U, h0, hseq, hfin0, rzbuf, flags);

    // ax1 = hseq @ Wx[1] + bx[1]
    gemm_kernel<false, true><<<dim3(1536 / 64, MROWS / 64), 256, 0, stream>>>(
        hseq, nullptr, Wx + 3 * HH, bx + 1536, axbuf, MROWS, 1536, HID);

    // layer-1 scan
    scan_coop_kernel<<<NBLK, NTHR, 0, stream>>>(
        axbuf, U + 3 * HH, h0 + BATCH * HID, hseq, hfin1, rzbuf, flags + NBLK);

    // logits = tops @ Wy^T + by
    gemm_kernel<false, false><<<dim3((VOCAB + 63) / 64, MROWS / 64), 256, 0, stream>>>(
        hseq, nullptr, Wy, by, out, MROWS, VOCAB, HID);
}